// Round 3
// baseline (407.398 us; speedup 1.0000x reference)
//
#include <hip/hip_runtime.h>

// Problem constants (fixed by reference): B=4, S=2048, DIN=4096, DOUT=4096
#define GM 8192   // M = B*S
#define GN 4096   // N = DOUT
#define GK 4096   // K = DIN

#define BM 128
#define BN 256
#define BK 64     // bytes of K per tile (i8)

using int4v = __attribute__((ext_vector_type(4))) int;

// ---------------- fused quantization ----------------
// blocks [0, 8192):    x_int8 = (int)(x*iscale)        (trunc toward zero)
// blocks [8192,12288): w_int8 = rintf(w*wscale[row])   (round half-even)
// Each thread handles 16 floats -> one uint4 (16 B) store.
__global__ __launch_bounds__(256) void quant_both(
    const float4* __restrict__ x, uint4* __restrict__ xq,
    const float4* __restrict__ w, uint4* __restrict__ wq,
    const float* __restrict__ wscale, const float* __restrict__ iscale) {
    const int b = blockIdx.x;
    if (b < 8192) {
        const float s = *iscale;
        const int i = b * 256 + threadIdx.x;      // uint4 index
        unsigned int q[4];
#pragma unroll
        for (int j = 0; j < 4; ++j) {
            float4 v = x[i * 4 + j];
            int q0 = (int)(v.x * s);
            int q1 = (int)(v.y * s);
            int q2 = (int)(v.z * s);
            int q3 = (int)(v.w * s);
            q[j] = (unsigned int)(q0 & 0xff) | ((unsigned int)(q1 & 0xff) << 8)
                 | ((unsigned int)(q2 & 0xff) << 16) | ((unsigned int)(q3 & 0xff) << 24);
        }
        xq[i] = uint4{q[0], q[1], q[2], q[3]};
    } else {
        const int row = b - 8192;                 // one block per weight row
        const float s = wscale[row];
        const int i = row * 256 + threadIdx.x;    // uint4 index
        unsigned int q[4];
#pragma unroll
        for (int j = 0; j < 4; ++j) {
            float4 v = w[i * 4 + j];
            int q0 = (int)rintf(v.x * s);
            int q1 = (int)rintf(v.y * s);
            int q2 = (int)rintf(v.z * s);
            int q3 = (int)rintf(v.w * s);
            q[j] = (unsigned int)(q0 & 0xff) | ((unsigned int)(q1 & 0xff) << 8)
                 | ((unsigned int)(q2 & 0xff) << 16) | ((unsigned int)(q3 & 0xff) << 24);
        }
        wq[i] = uint4{q[0], q[1], q[2], q[3]};
    }
}

// ---------------- int8 GEMM, double-buffered LDS ----------------
// Block tile 128x256, BK=64. 4 waves, each computes 64x128 (4x8 of 16x16x64).
// XOR-swizzled LDS (round-2, verified conflict-free): chunk (row,kc) stored at
// row*64 + (kc ^ ((row>>1)&3))*16; applied by permuting the global source
// chunk per lane (global_load_lds dest is fixed at base+lane*16).
// Double buffer: DMA for iter k+1 issued BEFORE compute of iter k, so the
// end-of-iter barrier's vmcnt(0) drain finds the DMA already complete.
__global__ __launch_bounds__(256, 2) void qlinear_gemm_i8(
    const signed char* __restrict__ Aq,
    const signed char* __restrict__ Bq,
    const float* __restrict__ bias,
    const float* __restrict__ wscale,
    const float* __restrict__ iscale,
    float* __restrict__ C) {
    __shared__ signed char As[2][BM * BK];   // 2 x 8 KiB
    __shared__ signed char Bs[2][BN * BK];   // 2 x 16 KiB  (48 KiB total)

    const int tid  = threadIdx.x;
    const int wave = tid >> 6;
    const int lane = tid & 63;
    const int m0 = blockIdx.x * BM;
    const int n0 = blockIdx.y * BN;
    const int wm = (wave >> 1) * 64;     // {0,64}
    const int wn = (wave & 1) * 128;     // {0,128}

    int4v acc[4][8];
#pragma unroll
    for (int i = 0; i < 4; ++i)
#pragma unroll
        for (int j = 0; j < 8; ++j)
            acc[i][j] = int4v{0, 0, 0, 0};

    // staging: swizzled global k-chunk byte offset for this lane
    const int kcl = ((lane & 3) ^ ((lane >> 3) & 3)) * 16;
    const int segA = wave * 2;           // A: wave stages segments {2w,2w+1}
    const signed char* gA = Aq + (size_t)(m0 + segA * 16 + (lane >> 2)) * GK + kcl;
    const int ldsA = segA * 1024 + lane * 16;
    const int segB = wave * 4;           // B: wave stages segments {4w..4w+3}
    const signed char* gB = Bq + (size_t)(n0 + segB * 16 + (lane >> 2)) * GK + kcl;
    const int ldsB = segB * 1024 + lane * 16;

    // LDS fragment read offsets (A-operand layout for 16x16x64 i8:
    // elem[m = lane&15][k = (lane>>4)*16 + j]); swizzled chunk position:
    const int pos = ((lane >> 4) ^ ((lane >> 1) & 3)) * 16;
    const int fAo = (wm + (lane & 15)) * BK + pos;
    const int fBo = (wn + (lane & 15)) * BK + pos;

#define GLL16(g, l)                                                     \
    __builtin_amdgcn_global_load_lds(                                   \
        (__attribute__((address_space(1))) void*)(void*)(g),            \
        (__attribute__((address_space(3))) void*)(l), 16, 0, 0)

#define STAGE(buf, k)                                                   \
    do {                                                                \
        GLL16(gA + (k), &As[buf][ldsA]);                                \
        GLL16(gA + (size_t)16 * GK + (k), &As[buf][ldsA + 1024]);       \
        GLL16(gB + (k), &Bs[buf][ldsB]);                                \
        GLL16(gB + (size_t)16 * GK + (k), &Bs[buf][ldsB + 1024]);       \
        GLL16(gB + (size_t)32 * GK + (k), &Bs[buf][ldsB + 2048]);       \
        GLL16(gB + (size_t)48 * GK + (k), &Bs[buf][ldsB + 3072]);       \
    } while (0)

    STAGE(0, 0);
    __syncthreads();

    for (int k0 = 0; k0 < GK; k0 += BK) {
        const int cur = (k0 >> 6) & 1;
        const int nxt = cur ^ 1;
        if (k0 + BK < GK) STAGE(nxt, k0 + BK);   // prefetch before compute

        const signed char* fA = &As[cur][fAo];
        const signed char* fB = &Bs[cur][fBo];
        int4v a[4], b[8];
#pragma unroll
        for (int i = 0; i < 4; ++i)
            a[i] = *(const int4v*)(fA + i * 16 * BK);
#pragma unroll
        for (int j = 0; j < 8; ++j)
            b[j] = *(const int4v*)(fB + j * 16 * BK);
#pragma unroll
        for (int mi = 0; mi < 4; ++mi)
#pragma unroll
            for (int ni = 0; ni < 8; ++ni)
                acc[mi][ni] = __builtin_amdgcn_mfma_i32_16x16x64_i8(
                    a[mi], b[ni], acc[mi][ni], 0, 0, 0);
        __syncthreads();   // drains prefetch DMA (already landed) + guards cur
    }

    // epilogue: C/D layout col=lane&15, row=(lane>>4)*4+reg
    const float isc = *iscale;
#pragma unroll
    for (int ni = 0; ni < 8; ++ni) {
        const int col = n0 + wn + ni * 16 + (lane & 15);
        const float bs = bias[col];
        const float inv = 1.0f / (wscale[col] * isc);   // 1/1024: exact (pow2)
#pragma unroll
        for (int mi = 0; mi < 4; ++mi) {
            const int row0 = m0 + wm + mi * 16 + (lane >> 4) * 4;
#pragma unroll
            for (int r = 0; r < 4; ++r) {
                C[(size_t)(row0 + r) * GN + col] =
                    ((float)acc[mi][ni][r] + bs) * inv;
            }
        }
    }
#undef STAGE
#undef GLL16
}

extern "C" void kernel_launch(void* const* d_in, const int* in_sizes, int n_in,
                              void* d_out, int out_size, void* d_ws, size_t ws_size,
                              hipStream_t stream) {
    const float* x      = (const float*)d_in[0];  // (4,2048,4096)
    const float* w      = (const float*)d_in[1];  // (4096,4096)
    const float* bias   = (const float*)d_in[2];  // (4096,)
    const float* wscale = (const float*)d_in[3];  // (4096,)
    const float* iscale = (const float*)d_in[4];  // (1,)
    float* out = (float*)d_out;

    signed char* xq = (signed char*)d_ws;                       // 32 MiB
    signed char* wq = xq + (size_t)GM * GK;                     // 16 MiB

    // 8192 x-blocks + 4096 w-blocks, 16 floats/thread, uint4 stores
    quant_both<<<12288, 256, 0, stream>>>((const float4*)x, (uint4*)xq,
                                          (const float4*)w, (uint4*)wq,
                                          wscale, iscale);

    dim3 grid(GM / BM, GN / BN);   // 64 x 16 = 1024 blocks
    qlinear_gemm_i8<<<grid, 256, 0, stream>>>(xq, wq, bias, wscale, iscale, out);
}